// Round 4
// baseline (177.067 us; speedup 1.0000x reference)
//
#include <hip/hip_runtime.h>
#include <stdint.h>
#include <stddef.h>

// GraphCoarsenLayer: out = x@W_self + mean(x[nbr[:, :16]])@W_neigh
//                        + mean(x[nbr[:,16:]])@W_coarsen + (b_self+b_neigh+b_coarsen)
// R4: fused gather+GEMM. Per block (64 rows x O=256): gather agg_s/agg_u (fp8 table)
// into LDS, then a barrier-free K=768 MFMA loop: A k<256 from chunked bf16 global,
// A k>=256 from agg LDS, B from chunked Wb global — all register-prefetched.
// Eliminates the 102 MB agg HBM round-trip and all staging barriers.

#define NN   50000
#define NPAD 50048          // multiple of 64
#define ODIM 256

typedef __bf16 bf16x8 __attribute__((ext_vector_type(8)));
typedef float  f32x4  __attribute__((ext_vector_type(4)));
typedef float  f32x2  __attribute__((ext_vector_type(2)));
typedef unsigned short u16x8 __attribute__((ext_vector_type(8)));
typedef unsigned short u16x4 __attribute__((ext_vector_type(4)));

static __device__ __forceinline__ unsigned short f2b(float f) {
    unsigned u = __builtin_bit_cast(unsigned, f);
    u += 0x7fffu + ((u >> 16) & 1u);          // round-to-nearest-even
    return (unsigned short)(u >> 16);
}

// ---------------- kernel 1: pack weights (K-chunked layout) + bias sum ----------
// Wb element layout: [g*256 + n]*8 + j  where k = g*8 + j  (g = 0..95)
__global__ void k_prep_w(const float* __restrict__ Wself, const float* __restrict__ bself,
                         const float* __restrict__ Wneigh, const float* __restrict__ bneigh,
                         const float* __restrict__ Wcoar, const float* __restrict__ bcoar,
                         unsigned short* __restrict__ Wb, float* __restrict__ bias) {
    int k = blockIdx.x;      // 0..767
    int n = threadIdx.x;     // 0..255
    const float* W = (k < 256) ? Wself : (k < 512) ? Wneigh : Wcoar;
    int kl = k & 255;
    float v = W[(size_t)kl * ODIM + n];
    int g = k >> 3;
    int j = k & 7;
    Wb[((size_t)g * ODIM + n) * 8 + j] = f2b(v);
    if (k == 0) bias[n] = bself[n] + bneigh[n] + bcoar[n];
}

// ---------------- kernel 2: x (f32) -> Ax chunked bf16 [kc][NPAD][8] + X8 fp8 ---
__global__ void k_convert_x(const float* __restrict__ x, unsigned short* __restrict__ Ax,
                            unsigned char* __restrict__ X8) {
    int p = blockIdx.x * 256 + threadIdx.x;    // one 8-element chunk per thread
    if (p >= NN * 32) return;
    int i  = p >> 5;
    int c8 = p & 31;
    const f32x4* src = (const f32x4*)(x + (size_t)i * 256 + c8 * 8);
    f32x4 v0 = src[0], v1 = src[1];
    u16x8 o;
    o[0] = f2b(v0[0]); o[1] = f2b(v0[1]); o[2] = f2b(v0[2]); o[3] = f2b(v0[3]);
    o[4] = f2b(v1[0]); o[5] = f2b(v1[1]); o[6] = f2b(v1[2]); o[7] = f2b(v1[3]);
    *(u16x8*)(Ax + ((size_t)c8 * NPAD + i) * 8) = o;      // chunked: frag loads contiguous
    unsigned d0 = __builtin_amdgcn_cvt_pk_fp8_f32(v0[0], v0[1], 0, false);
    d0 = (unsigned)__builtin_amdgcn_cvt_pk_fp8_f32(v0[2], v0[3], d0, true);
    unsigned d1 = __builtin_amdgcn_cvt_pk_fp8_f32(v1[0], v1[1], 0, false);
    d1 = (unsigned)__builtin_amdgcn_cvt_pk_fp8_f32(v1[2], v1[3], d1, true);
    uint2 o8; o8.x = d0; o8.y = d1;
    *(uint2*)(X8 + (size_t)i * 256 + c8 * 8) = o8;
}

// ---------------- kernel 3: fused gather + GEMM --------------------------------
// 512 threads = 8 waves (2M x 4N); block tile 64 x 256; K = 768 in 24 steps of 32.
// agg LDS: [c8(64)][row(65 pad)][8] u16  (pad row-dim to 65 -> transpose-safe banks)
__global__ __launch_bounds__(512, 4) void k_fused(const unsigned short* __restrict__ Ax,
                                                  const unsigned char* __restrict__ X8,
                                                  const unsigned short* __restrict__ Wb,
                                                  const int* __restrict__ nbr,
                                                  const float* __restrict__ bias,
                                                  float* __restrict__ out) {
    __shared__ __align__(16) unsigned short agg[64 * 520];   // 66560 B
    const int tid  = threadIdx.x;
    const int wid  = tid >> 6;
    const int lane = tid & 63;
    const int row0 = blockIdx.x * 64;
    const int l15 = lane & 15, l4 = lane >> 4;

    // ---- phase 1: gather-mean into agg LDS ----
    {
        const int c8 = lane >> 1;          // 0..31 (column chunk within a 256 segment)
        const int jb = (lane & 1) * 4;     // 0 or 4
        for (int r = 0; r < 8; ++r) {
            const int i  = row0 + wid * 8 + r;
            const int ii = (i < NN) ? i : (NN - 1);          // tail clamp
            const int* nb = nbr + (size_t)ii * 32;
            float s0 = 0, s1 = 0, s2 = 0, s3 = 0, u0 = 0, u1 = 0, u2 = 0, u3 = 0;
#pragma unroll
            for (int j = 0; j < 32; ++j) {
                int idx = nb[j];
                unsigned d = *(const unsigned*)(X8 + (size_t)idx * 256 + lane * 4);
                f32x2 lo = __builtin_amdgcn_cvt_pk_f32_fp8(d, false);
                f32x2 hi = __builtin_amdgcn_cvt_pk_f32_fp8(d, true);
                if (j < 16) { s0 += lo[0]; s1 += lo[1]; s2 += hi[0]; s3 += hi[1]; }
                else        { u0 += lo[0]; u1 += lo[1]; u2 += hi[0]; u3 += hi[1]; }
            }
            const float rc = 1.0f / 16.0f;
            const int rl = wid * 8 + r;
            u16x4 os = { f2b(s0 * rc), f2b(s1 * rc), f2b(s2 * rc), f2b(s3 * rc) };
            u16x4 ou = { f2b(u0 * rc), f2b(u1 * rc), f2b(u2 * rc), f2b(u3 * rc) };
            *(u16x4*)&agg[c8 * 520 + rl * 8 + jb]        = os;   // k 256..511 part
            *(u16x4*)&agg[(c8 + 32) * 520 + rl * 8 + jb] = ou;   // k 512..767 part
        }
    }
    __syncthreads();   // agg is read-only from here on: no further barriers needed

    // ---- phase 2: barrier-free GEMM ----
    const int wm = (wid >> 2) * 32;        // 0 or 32
    const int wn = (wid & 3) * 64;         // 0,64,128,192
    f32x4 acc[2][4] = {};

    auto loadA = [&](int t, bf16x8* a) {
#pragma unroll
        for (int mi = 0; mi < 2; ++mi) {
            const int rl = wm + mi * 16 + l15;
            if (t < 8) {                   // folds: t is compile-time under full unroll
                const int kc = t * 4 + l4;
                a[mi] = *(const bf16x8*)(Ax + ((size_t)kc * NPAD + row0 + rl) * 8);
            } else {
                const int c8 = (t - 8) * 4 + l4;
                a[mi] = *(const bf16x8*)&agg[c8 * 520 + rl * 8];
            }
        }
    };
    auto loadB = [&](int t, bf16x8* b) {
        const int g = t * 4 + l4;          // 0..95
#pragma unroll
        for (int ni = 0; ni < 4; ++ni)
            b[ni] = *(const bf16x8*)(Wb + ((size_t)g * ODIM + wn + ni * 16 + l15) * 8);
    };
    auto mfma8 = [&](bf16x8* a, bf16x8* b) {
#pragma unroll
        for (int mi = 0; mi < 2; ++mi)
#pragma unroll
            for (int ni = 0; ni < 4; ++ni)
                acc[mi][ni] = __builtin_amdgcn_mfma_f32_16x16x32_bf16(
                    a[mi], b[ni], acc[mi][ni], 0, 0, 0);
    };

    bf16x8 a0[2], a1[2], b0[4], b1[4];     // named double-buffer (static indexing)
    loadA(0, a0); loadB(0, b0);
#pragma unroll
    for (int t = 0; t < 24; t += 2) {
        loadA(t + 1, a1); loadB(t + 1, b1);
        mfma8(a0, b0);
        if (t + 2 < 24) { loadA(t + 2, a0); loadB(t + 2, b0); }
        mfma8(a1, b1);
    }

    // ---- epilogue: bias + store (D layout: col=lane&15, row=(lane>>4)*4+r) ----
#pragma unroll
    for (int mi = 0; mi < 2; ++mi) {
        const int row = row0 + wm + mi * 16 + l4 * 4;
#pragma unroll
        for (int ni = 0; ni < 4; ++ni) {
            const int col = wn + ni * 16 + l15;
            const float bb = bias[col];
            f32x4 v = acc[mi][ni];
#pragma unroll
            for (int r = 0; r < 4; ++r) {
                const int rr = row + r;
                if (rr < NN) out[(size_t)rr * ODIM + col] = v[r] + bb;
            }
        }
    }
}

// ---------------- launch -------------------------------------------------------
extern "C" void kernel_launch(void* const* d_in, const int* in_sizes, int n_in,
                              void* d_out, int out_size, void* d_ws, size_t ws_size,
                              hipStream_t stream) {
    const float* x      = (const float*)d_in[0];
    const float* Wself  = (const float*)d_in[1];
    const float* bself  = (const float*)d_in[2];
    const float* Wneigh = (const float*)d_in[3];
    const float* bneigh = (const float*)d_in[4];
    const float* Wcoar  = (const float*)d_in[5];
    const float* bcoar  = (const float*)d_in[6];
    const int*   nbr    = (const int*)d_in[7];
    float* out = (float*)d_out;

    // workspace: Ax (25.6 MB) | X8 (12.8 MB) | Wb (384 KB) | bias (1 KB)  ~= 38.8 MB
    unsigned short* Ax   = (unsigned short*)d_ws;                  // 32 x NPAD x 8 bf16
    unsigned char*  X8   = (unsigned char*)(Ax + (size_t)32 * NPAD * 8);
    unsigned short* Wb   = (unsigned short*)(X8 + (size_t)NN * 256);
    float*          bias = (float*)(Wb + (size_t)96 * ODIM * 8);

    k_prep_w<<<768, 256, 0, stream>>>(Wself, bself, Wneigh, bneigh, Wcoar, bcoar, Wb, bias);
    k_convert_x<<<(NN * 32 + 255) / 256, 256, 0, stream>>>(x, Ax, X8);
    k_fused<<<NPAD / 64, 512, 0, stream>>>(Ax, X8, Wb, nbr, bias, out);
}

// Round 5
// 119.647 us; speedup vs baseline: 1.4799x; 1.4799x over previous
//
#include <hip/hip_runtime.h>
#include <stdint.h>
#include <stddef.h>

// GraphCoarsenLayer: out = x@W_self + mean(x[nbr[:, :16]])@W_neigh
//                        + mean(x[nbr[:,16:]])@W_coarsen + (b_self+b_neigh+b_coarsen)
// R5: split kernels (R4 fusion reverted — it serialized the gather behind a barrier).
// A stored K-chunked [g 0..95][row NPAD][8] bf16 so every GEMM staging load is 1KB
// contiguous; GEMM uses a 3-buffer pipeline with counted vmcnt (never drained to 0
// mid-loop), one barrier per K-step. Gather writes its agg chunks coalesced via an
// in-block LDS transpose (8 nodes/block).

#define NN   50000
#define NPAD 50048          // multiple of 128
#define ODIM 256

typedef __bf16 bf16x8 __attribute__((ext_vector_type(8)));
typedef float  f32x4  __attribute__((ext_vector_type(4)));
typedef float  f32x2  __attribute__((ext_vector_type(2)));
typedef unsigned short u16x8 __attribute__((ext_vector_type(8)));
typedef unsigned short u16x4 __attribute__((ext_vector_type(4)));

static __device__ __forceinline__ unsigned short f2b(float f) {
    unsigned u = __builtin_bit_cast(unsigned, f);
    u += 0x7fffu + ((u >> 16) & 1u);          // round-to-nearest-even
    return (unsigned short)(u >> 16);
}

// ---------------- kernel 1: pack weights (K-chunked) + bias sum ----------------
// Wb layout: [g*256 + n]*8 + j  where k = g*8 + j  (g = 0..95)
__global__ void k_prep_w(const float* __restrict__ Wself, const float* __restrict__ bself,
                         const float* __restrict__ Wneigh, const float* __restrict__ bneigh,
                         const float* __restrict__ Wcoar, const float* __restrict__ bcoar,
                         unsigned short* __restrict__ Wb, float* __restrict__ bias) {
    int k = blockIdx.x;      // 0..767
    int n = threadIdx.x;     // 0..255
    const float* W = (k < 256) ? Wself : (k < 512) ? Wneigh : Wcoar;
    int kl = k & 255;
    float v = W[(size_t)kl * ODIM + n];
    int g = k >> 3;
    int j = k & 7;
    Wb[((size_t)g * ODIM + n) * 8 + j] = f2b(v);
    if (k == 0) bias[n] = bself[n] + bneigh[n] + bcoar[n];
}

// ---------------- kernel 2: x (f32) -> Ax chunked g<32 (bf16) + X8 fp8 ---------
__global__ void k_convert_x(const float* __restrict__ x, unsigned short* __restrict__ Ax,
                            unsigned char* __restrict__ X8) {
    int p = blockIdx.x * 256 + threadIdx.x;    // one 8-element chunk per thread
    if (p >= NN * 32) return;
    int i  = p >> 5;
    int c8 = p & 31;
    const f32x4* src = (const f32x4*)(x + (size_t)i * 256 + c8 * 8);
    f32x4 v0 = src[0], v1 = src[1];
    u16x8 o;
    o[0] = f2b(v0[0]); o[1] = f2b(v0[1]); o[2] = f2b(v0[2]); o[3] = f2b(v0[3]);
    o[4] = f2b(v1[0]); o[5] = f2b(v1[1]); o[6] = f2b(v1[2]); o[7] = f2b(v1[3]);
    *(u16x8*)(Ax + ((size_t)c8 * NPAD + i) * 8) = o;      // chunked layout
    unsigned d0 = __builtin_amdgcn_cvt_pk_fp8_f32(v0[0], v0[1], 0, false);
    d0 = (unsigned)__builtin_amdgcn_cvt_pk_fp8_f32(v0[2], v0[3], d0, true);
    unsigned d1 = __builtin_amdgcn_cvt_pk_fp8_f32(v1[0], v1[1], 0, false);
    d1 = (unsigned)__builtin_amdgcn_cvt_pk_fp8_f32(v1[2], v1[3], d1, true);
    uint2 o8; o8.x = d0; o8.y = d1;
    *(uint2*)(X8 + (size_t)i * 256 + c8 * 8) = o8;
}

// ---------------- kernel 3: gather-mean -> Ax chunks g 32..95 ------------------
// 8 waves = 8 nodes per block (wave-per-node keeps full TLP); results staged in
// LDS then written out transposed so HBM writes are 128B-contiguous.
__global__ __launch_bounds__(512) void k_gather(const int* __restrict__ nbr,
                                                const unsigned char* __restrict__ X8,
                                                unsigned short* __restrict__ Ax) {
    __shared__ unsigned short aggl[8][512];
    const int wid  = threadIdx.x >> 6;
    const int lane = threadIdx.x & 63;
    const int i = blockIdx.x * 8 + wid;        // NN = 6250*8 exactly
    const int* nb = nbr + (size_t)i * 32;
    float s0 = 0, s1 = 0, s2 = 0, s3 = 0, u0 = 0, u1 = 0, u2 = 0, u3 = 0;
#pragma unroll
    for (int j = 0; j < 32; ++j) {
        int idx = nb[j];
        unsigned d = *(const unsigned*)(X8 + (size_t)idx * 256 + lane * 4);
        f32x2 lo = __builtin_amdgcn_cvt_pk_f32_fp8(d, false);
        f32x2 hi = __builtin_amdgcn_cvt_pk_f32_fp8(d, true);
        if (j < 16) { s0 += lo[0]; s1 += lo[1]; s2 += hi[0]; s3 += hi[1]; }
        else        { u0 += lo[0]; u1 += lo[1]; u2 += hi[0]; u3 += hi[1]; }
    }
    const float rc = 1.0f / 16.0f;
    u16x4 os = { f2b(s0 * rc), f2b(s1 * rc), f2b(s2 * rc), f2b(s3 * rc) };
    u16x4 ou = { f2b(u0 * rc), f2b(u1 * rc), f2b(u2 * rc), f2b(u3 * rc) };
    *(u16x4*)&aggl[wid][lane * 4]       = os;   // cols 0..255   (k 256..511)
    *(u16x4*)&aggl[wid][256 + lane * 4] = ou;   // cols 256..511 (k 512..767)
    __syncthreads();
    // write-out: thread tau -> chunk (gl = tau>>3, r = tau&7); 8 consecutive threads
    // write 8 consecutive rows of the same chunk = 128B contiguous in Ax.
    const int tau = threadIdx.x;
    const int gl = tau >> 3, r = tau & 7;
    u16x8 v = *(const u16x8*)&aggl[r][gl * 8];
    *(u16x8*)(Ax + ((size_t)(32 + gl) * NPAD + blockIdx.x * 8 + r) * 8) = v;
}

// ---------------- kernel 4: GEMM  out[N,256] = A[N,768] @ Wb + bias ------------
// 128x128 tile, BK=32, 4 waves (2x2 of 64x64), 3-buffer LDS pipeline (48KB),
// counted vmcnt(4) per K-step, ONE barrier per K-step, 3 blocks/CU.
#define BM 128
#define BN 128
#define BK 32
#define NT 24               // 768 / 32

__global__ __launch_bounds__(256, 3) void k_gemm(const unsigned short* __restrict__ Ax,
                                                 const unsigned short* __restrict__ Wb,
                                                 const float* __restrict__ bias,
                                                 float* __restrict__ out) {
    __shared__ __align__(16) unsigned short lds[3][2][4096];  // 48 KB
    const int tid  = threadIdx.x;
    const int wid  = tid >> 6;
    const int lane = tid & 63;
    const int bid  = blockIdx.x;
    const int mt = bid >> 1, nt = bid & 1;
    const int row0 = mt * BM;
    const int n0   = nt * BN;
    const int wm = (wid >> 1) * 64, wn = (wid & 1) * 64;
    const int l15 = lane & 15, l4 = lane >> 4;

    f32x4 acc[4][4] = {};

    // stage one K-tile (A 128x32 + B 32x128 = 16 x 1KB units; 4 units per wave).
    // Every source is 1KB contiguous (chunked layouts) -> perfectly coalesced.
    auto stage = [&](int buf, int t) {
#pragma unroll
        for (int q4 = 0; q4 < 4; ++q4) {
            const int q    = (wid & 1) * 4 + q4;   // 0..7
            const int kc   = q >> 1;               // 0..3
            const int half = q & 1;
            const int g    = t * 4 + kc;           // global 8-K chunk 0..95
            if (wid < 2) {
                const unsigned short* src =
                    Ax + ((size_t)g * NPAD + row0 + half * 64 + lane) * 8;
                unsigned short* dst = &lds[buf][0][kc * 1024 + half * 512];
                __builtin_amdgcn_global_load_lds(
                    (const __attribute__((address_space(1))) void*)src,
                    (__attribute__((address_space(3))) void*)dst, 16, 0, 0);
            } else {
                const unsigned short* src =
                    Wb + ((size_t)g * ODIM + n0 + half * 64 + lane) * 8;
                unsigned short* dst = &lds[buf][1][kc * 1024 + half * 512];
                __builtin_amdgcn_global_load_lds(
                    (const __attribute__((address_space(1))) void*)src,
                    (__attribute__((address_space(3))) void*)dst, 16, 0, 0);
            }
        }
    };

    stage(0, 0);
    stage(1, 1);
#pragma unroll
    for (int t = 0; t < NT; ++t) {
        // own 4 loads of tile t complete; tile t+1's stay in flight (counted wait)
        if (t < NT - 1) asm volatile("s_waitcnt vmcnt(4)" ::: "memory");
        else            asm volatile("s_waitcnt vmcnt(0)" ::: "memory");
        __builtin_amdgcn_s_barrier();          // all waves' tile-t loads now visible
        __builtin_amdgcn_sched_barrier(0);     // no ds_read hoisting above barrier
        if (t + 2 < NT) stage((t + 2) % 3, t + 2);   // restage buf last read at t-1
        const int buf = t % 3;
        bf16x8 af[4], bfr[4];
#pragma unroll
        for (int mi = 0; mi < 4; ++mi)
            af[mi] = *(const bf16x8*)&lds[buf][0][l4 * 1024 + (wm + mi * 16 + l15) * 8];
#pragma unroll
        for (int ni = 0; ni < 4; ++ni)
            bfr[ni] = *(const bf16x8*)&lds[buf][1][l4 * 1024 + (wn + ni * 16 + l15) * 8];
#pragma unroll
        for (int mi = 0; mi < 4; ++mi)
#pragma unroll
            for (int ni = 0; ni < 4; ++ni)
                acc[mi][ni] = __builtin_amdgcn_mfma_f32_16x16x32_bf16(
                    af[mi], bfr[ni], acc[mi][ni], 0, 0, 0);
    }

    // epilogue: D layout col=lane&15, row=(lane>>4)*4+r
#pragma unroll
    for (int mi = 0; mi < 4; ++mi) {
        const int row = row0 + wm + mi * 16 + l4 * 4;
#pragma unroll
        for (int ni = 0; ni < 4; ++ni) {
            const int col = n0 + wn + ni * 16 + l15;
            const float bb = bias[col];
            f32x4 v = acc[mi][ni];
#pragma unroll
            for (int r = 0; r < 4; ++r) {
                const int rr = row + r;
                if (rr < NN) out[(size_t)rr * ODIM + col] = v[r] + bb;
            }
        }
    }
}

// ---------------- launch -------------------------------------------------------
extern "C" void kernel_launch(void* const* d_in, const int* in_sizes, int n_in,
                              void* d_out, int out_size, void* d_ws, size_t ws_size,
                              hipStream_t stream) {
    const float* x      = (const float*)d_in[0];
    const float* Wself  = (const float*)d_in[1];
    const float* bself  = (const float*)d_in[2];
    const float* Wneigh = (const float*)d_in[3];
    const float* bneigh = (const float*)d_in[4];
    const float* Wcoar  = (const float*)d_in[5];
    const float* bcoar  = (const float*)d_in[6];
    const int*   nbr    = (const int*)d_in[7];
    float* out = (float*)d_out;

    // workspace: Ax (76.9 MB, 96 chunks x NPAD x 8 bf16) | X8 (12.8) | Wb | bias ~= 90.1 MB
    unsigned short* Ax   = (unsigned short*)d_ws;
    unsigned char*  X8   = (unsigned char*)(Ax + (size_t)96 * NPAD * 8);
    unsigned short* Wb   = (unsigned short*)(X8 + (size_t)NN * 256);
    float*          bias = (float*)(Wb + (size_t)96 * ODIM * 8);

    k_prep_w<<<768, 256, 0, stream>>>(Wself, bself, Wneigh, bneigh, Wcoar, bcoar, Wb, bias);
    k_convert_x<<<(NN * 32 + 255) / 256, 256, 0, stream>>>(x, Ax, X8);
    k_gather<<<NN / 8, 512, 0, stream>>>(nbr, X8, Ax);
    k_gemm<<<(NPAD / BM) * 2, 256, 0, stream>>>(Ax, Wb, bias, out);
}

// Round 6
// 109.592 us; speedup vs baseline: 1.6157x; 1.0917x over previous
//
#include <hip/hip_runtime.h>
#include <stdint.h>
#include <stddef.h>

// GraphCoarsenLayer: out = x@W_self + mean(x[nbr[:, :16]])@W_neigh
//                        + mean(x[nbr[:,16:]])@W_coarsen + (b_self+b_neigh+b_coarsen)
// R6: GEMM rewritten LDS-free / barrier-free. A and Wb are stored K-chunked
// ([g][row][8] / [g][n][8]) so each MFMA fragment is a contiguous 16B per lane —
// loaded global->register directly with a depth-3 register pipeline. No LDS, no
// syncthreads, no vmcnt drains. XCD swizzle keeps same-mt (2 nt) blocks on one XCD
// so A re-reads hit XCD-local L2. Gather/convert unchanged from R5.

#define NN   50000
#define NPAD 50176          // multiple of 128; 392 mt-tiles exactly
#define ODIM 256

typedef __bf16 bf16x8 __attribute__((ext_vector_type(8)));
typedef float  f32x4  __attribute__((ext_vector_type(4)));
typedef float  f32x2  __attribute__((ext_vector_type(2)));
typedef unsigned short u16x8 __attribute__((ext_vector_type(8)));
typedef unsigned short u16x4 __attribute__((ext_vector_type(4)));

static __device__ __forceinline__ unsigned short f2b(float f) {
    unsigned u = __builtin_bit_cast(unsigned, f);
    u += 0x7fffu + ((u >> 16) & 1u);          // round-to-nearest-even
    return (unsigned short)(u >> 16);
}

// ---------------- kernel 1: pack weights (K-chunked) + bias sum ----------------
// Wb layout: [g*256 + n]*8 + j  where k = g*8 + j  (g = 0..95)
__global__ void k_prep_w(const float* __restrict__ Wself, const float* __restrict__ bself,
                         const float* __restrict__ Wneigh, const float* __restrict__ bneigh,
                         const float* __restrict__ Wcoar, const float* __restrict__ bcoar,
                         unsigned short* __restrict__ Wb, float* __restrict__ bias) {
    int k = blockIdx.x;      // 0..767
    int n = threadIdx.x;     // 0..255
    const float* W = (k < 256) ? Wself : (k < 512) ? Wneigh : Wcoar;
    int kl = k & 255;
    float v = W[(size_t)kl * ODIM + n];
    int g = k >> 3;
    int j = k & 7;
    Wb[((size_t)g * ODIM + n) * 8 + j] = f2b(v);
    if (k == 0) bias[n] = bself[n] + bneigh[n] + bcoar[n];
}

// ---------------- kernel 2: x (f32) -> Ax chunked g<32 (bf16) + X8 fp8 ---------
__global__ void k_convert_x(const float* __restrict__ x, unsigned short* __restrict__ Ax,
                            unsigned char* __restrict__ X8) {
    int p = blockIdx.x * 256 + threadIdx.x;    // one 8-element chunk per thread
    if (p >= NN * 32) return;
    int i  = p >> 5;
    int c8 = p & 31;
    const f32x4* src = (const f32x4*)(x + (size_t)i * 256 + c8 * 8);
    f32x4 v0 = src[0], v1 = src[1];
    u16x8 o;
    o[0] = f2b(v0[0]); o[1] = f2b(v0[1]); o[2] = f2b(v0[2]); o[3] = f2b(v0[3]);
    o[4] = f2b(v1[0]); o[5] = f2b(v1[1]); o[6] = f2b(v1[2]); o[7] = f2b(v1[3]);
    *(u16x8*)(Ax + ((size_t)c8 * NPAD + i) * 8) = o;      // chunked layout
    unsigned d0 = __builtin_amdgcn_cvt_pk_fp8_f32(v0[0], v0[1], 0, false);
    d0 = (unsigned)__builtin_amdgcn_cvt_pk_fp8_f32(v0[2], v0[3], d0, true);
    unsigned d1 = __builtin_amdgcn_cvt_pk_fp8_f32(v1[0], v1[1], 0, false);
    d1 = (unsigned)__builtin_amdgcn_cvt_pk_fp8_f32(v1[2], v1[3], d1, true);
    uint2 o8; o8.x = d0; o8.y = d1;
    *(uint2*)(X8 + (size_t)i * 256 + c8 * 8) = o8;
}

// ---------------- kernel 3: gather-mean -> Ax chunks g 32..95 ------------------
// 8 waves = 8 nodes per block (wave-per-node keeps full TLP); LDS transpose so
// HBM writes are 128B-contiguous.
__global__ __launch_bounds__(512) void k_gather(const int* __restrict__ nbr,
                                                const unsigned char* __restrict__ X8,
                                                unsigned short* __restrict__ Ax) {
    __shared__ unsigned short aggl[8][512];
    const int wid  = threadIdx.x >> 6;
    const int lane = threadIdx.x & 63;
    const int i = blockIdx.x * 8 + wid;        // NN = 6250*8 exactly
    const int* nb = nbr + (size_t)i * 32;
    float s0 = 0, s1 = 0, s2 = 0, s3 = 0, u0 = 0, u1 = 0, u2 = 0, u3 = 0;
#pragma unroll
    for (int j = 0; j < 32; ++j) {
        int idx = nb[j];
        unsigned d = *(const unsigned*)(X8 + (size_t)idx * 256 + lane * 4);
        f32x2 lo = __builtin_amdgcn_cvt_pk_f32_fp8(d, false);
        f32x2 hi = __builtin_amdgcn_cvt_pk_f32_fp8(d, true);
        if (j < 16) { s0 += lo[0]; s1 += lo[1]; s2 += hi[0]; s3 += hi[1]; }
        else        { u0 += lo[0]; u1 += lo[1]; u2 += hi[0]; u3 += hi[1]; }
    }
    const float rc = 1.0f / 16.0f;
    u16x4 os = { f2b(s0 * rc), f2b(s1 * rc), f2b(s2 * rc), f2b(s3 * rc) };
    u16x4 ou = { f2b(u0 * rc), f2b(u1 * rc), f2b(u2 * rc), f2b(u3 * rc) };
    *(u16x4*)&aggl[wid][lane * 4]       = os;   // cols 0..255   (k 256..511)
    *(u16x4*)&aggl[wid][256 + lane * 4] = ou;   // cols 256..511 (k 512..767)
    __syncthreads();
    const int tau = threadIdx.x;
    const int gl = tau >> 3, r = tau & 7;       // 64 chunks x 8 rows
    u16x8 v = *(const u16x8*)&aggl[r][gl * 8];
    *(u16x8*)(Ax + ((size_t)(32 + gl) * NPAD + blockIdx.x * 8 + r) * 8) = v;
}

// ---------------- kernel 4: GEMM  out[N,256] = A[N,768] @ Wb + bias ------------
// LDS-free, barrier-free. Tile 128x128, 4 waves (2x2), wave 64x64.
// Fragments loaded global->register (contiguous 16B/lane), depth-3 pipeline.
#define NT 24               // 768 / 32

__global__ __launch_bounds__(256, 2) void k_gemm(const unsigned short* __restrict__ Ax,
                                                 const unsigned short* __restrict__ Wb,
                                                 const float* __restrict__ bias,
                                                 float* __restrict__ out) {
    const int tid  = threadIdx.x;
    const int wid  = tid >> 6;
    const int lane = tid & 63;
    const int l15 = lane & 15, l4 = lane >> 4;

    // XCD swizzle: group of 16 bids = 8 mt x 2 nt; same-mt pair shares bid%8 (one XCD)
    const int bid = blockIdx.x;                // 784 = 49 groups * 16
    const int g16 = bid >> 4, r16 = bid & 15;
    const int mt = g16 * 8 + (r16 & 7);        // 0..391
    const int nt = r16 >> 3;                   // 0..1
    const int row0 = mt * 128;
    const int n0   = nt * 128;
    const int wm = (wid >> 1) * 64, wn = (wid & 1) * 64;

    f32x4 acc[4][4] = {};

    auto loadA = [&](bf16x8* a, int t) {
        const int g = t * 4 + l4;              // K-chunk 0..95
#pragma unroll
        for (int mi = 0; mi < 4; ++mi)
            a[mi] = *(const bf16x8*)(Ax + ((size_t)g * NPAD + row0 + wm + mi * 16 + l15) * 8);
    };
    auto loadB = [&](bf16x8* b, int t) {
        const int g = t * 4 + l4;
#pragma unroll
        for (int ni = 0; ni < 4; ++ni)
            b[ni] = *(const bf16x8*)(Wb + ((size_t)g * ODIM + n0 + wn + ni * 16 + l15) * 8);
    };

    bf16x8 As[3][4], Bs[3][4];                 // depth-3 slots; all indices static
    loadA(As[0], 0); loadB(Bs[0], 0);
    loadA(As[1], 1); loadB(Bs[1], 1);
#pragma unroll
    for (int t = 0; t < NT; ++t) {
        if (t + 2 < NT) { loadA(As[(t + 2) % 3], t + 2); loadB(Bs[(t + 2) % 3], t + 2); }
        bf16x8* a = As[t % 3];
        bf16x8* b = Bs[t % 3];
#pragma unroll
        for (int mi = 0; mi < 4; ++mi)
#pragma unroll
            for (int ni = 0; ni < 4; ++ni)
                acc[mi][ni] = __builtin_amdgcn_mfma_f32_16x16x32_bf16(
                    a[mi], b[ni], acc[mi][ni], 0, 0, 0);
    }

    // epilogue: D layout col=lane&15, row=(lane>>4)*4+r
#pragma unroll
    for (int mi = 0; mi < 4; ++mi) {
        const int row = row0 + wm + mi * 16 + l4 * 4;
#pragma unroll
        for (int ni = 0; ni < 4; ++ni) {
            const int col = n0 + wn + ni * 16 + l15;
            const float bb = bias[col];
            f32x4 v = acc[mi][ni];
#pragma unroll
            for (int r = 0; r < 4; ++r) {
                const int rr = row + r;
                if (rr < NN) out[(size_t)rr * ODIM + col] = v[r] + bb;
            }
        }
    }
}

// ---------------- launch -------------------------------------------------------
extern "C" void kernel_launch(void* const* d_in, const int* in_sizes, int n_in,
                              void* d_out, int out_size, void* d_ws, size_t ws_size,
                              hipStream_t stream) {
    const float* x      = (const float*)d_in[0];
    const float* Wself  = (const float*)d_in[1];
    const float* bself  = (const float*)d_in[2];
    const float* Wneigh = (const float*)d_in[3];
    const float* bneigh = (const float*)d_in[4];
    const float* Wcoar  = (const float*)d_in[5];
    const float* bcoar  = (const float*)d_in[6];
    const int*   nbr    = (const int*)d_in[7];
    float* out = (float*)d_out;

    // workspace: Ax (77.1 MB, 96 chunks x NPAD x 8 bf16) | X8 (12.8) | Wb | bias ~= 90.3 MB
    unsigned short* Ax   = (unsigned short*)d_ws;
    unsigned char*  X8   = (unsigned char*)(Ax + (size_t)96 * NPAD * 8);
    unsigned short* Wb   = (unsigned short*)(X8 + (size_t)NN * 256);
    float*          bias = (float*)(Wb + (size_t)96 * ODIM * 8);

    k_prep_w<<<768, 256, 0, stream>>>(Wself, bself, Wneigh, bneigh, Wcoar, bcoar, Wb, bias);
    k_convert_x<<<(NN * 32 + 255) / 256, 256, 0, stream>>>(x, Ax, X8);
    k_gather<<<NN / 8, 512, 0, stream>>>(nbr, X8, Ax);
    k_gemm<<<784, 256, 0, stream>>>(Ax, Wb, bias, out);
}